// Round 1
// baseline (678.543 us; speedup 1.0000x reference)
//
#include <hip/hip_runtime.h>
#include <math.h>

// Problem constants
static constexpr int Bc  = 8;
static constexpr int Tc  = 128;
static constexpr int Dc  = 512;
static constexpr int LAc = 2;
static constexpr int LRc = 2;
static constexpr int Hc  = 4;
static constexpr int DKc = 128;
static constexpr int DFFc = 2048;
static constexpr int BTc = 1024;   // B*T

// ---------------- LayerNorm: one wave (64 lanes) per 512-wide row ----------
__global__ __launch_bounds__(256) void ln_kernel(const float* __restrict__ x,
    const float* __restrict__ g, const float* __restrict__ bb,
    float* __restrict__ out, int rows)
{
  int gid = blockIdx.x * 256 + threadIdx.x;
  int row = gid >> 6;
  int lane = threadIdx.x & 63;
  if (row >= rows) return;
  const float* xr = x + (size_t)row * Dc + lane * 8;
  float4 a = *(const float4*)xr;
  float4 c = *(const float4*)(xr + 4);
  float s  = a.x + a.y + a.z + a.w + c.x + c.y + c.z + c.w;
  float ss = a.x*a.x + a.y*a.y + a.z*a.z + a.w*a.w
           + c.x*c.x + c.y*c.y + c.z*c.z + c.w*c.w;
  #pragma unroll
  for (int off = 32; off > 0; off >>= 1) {
    s  += __shfl_xor(s, off);
    ss += __shfl_xor(ss, off);
  }
  float mu  = s * (1.0f/512.0f);
  float var = ss * (1.0f/512.0f) - mu*mu;
  float rstd = rsqrtf(var + 1e-5f);
  const float* gp = g + lane*8;
  const float* bp = bb + lane*8;
  float4 g0 = *(const float4*)gp, g1 = *(const float4*)(gp+4);
  float4 b0 = *(const float4*)bp, b1 = *(const float4*)(bp+4);
  float4 o0, o1;
  o0.x = (a.x-mu)*rstd*g0.x + b0.x;
  o0.y = (a.y-mu)*rstd*g0.y + b0.y;
  o0.z = (a.z-mu)*rstd*g0.z + b0.z;
  o0.w = (a.w-mu)*rstd*g0.w + b0.w;
  o1.x = (c.x-mu)*rstd*g1.x + b1.x;
  o1.y = (c.y-mu)*rstd*g1.y + b1.y;
  o1.z = (c.z-mu)*rstd*g1.z + b1.z;
  o1.w = (c.w-mu)*rstd*g1.w + b1.w;
  float* op = out + (size_t)row * Dc + lane * 8;
  *(float4*)op = o0;
  *(float4*)(op+4) = o1;
}

// ---------------- GELU ----------------
__device__ __forceinline__ float gelu_f(float v) {
  float t = tanhf(0.7978845608028654f * (v + 0.044715f * v * v * v));
  return 0.5f * v * (1.0f + t);
}

// ---------------- Generic fp32 tiled GEMM: C = A(MxK) * B(KxN) (+bias)(+gelu)(+res)
// 64x64 tile, BK=16, 256 threads, 4x4 per thread.
template<bool TRANSB, bool GELU_>
__global__ __launch_bounds__(256) void gemm_kernel(
    const float* __restrict__ A, int lda,
    const float* __restrict__ Bm, int ldb,
    const float* __restrict__ bias,
    const float* __restrict__ res,
    float* __restrict__ C, int ldc,
    int M, int N, int K)
{
  __shared__ float As[16][68];
  __shared__ float Bs[16][68];
  int tid = threadIdx.x;
  int bm = blockIdx.y * 64;
  int bn = blockIdx.x * 64;
  int tx = tid & 15;
  int ty = tid >> 4;
  float acc[4][4] = {};
  int ar = tid >> 2;          // 0..63
  int ac = (tid & 3) << 2;    // 0,4,8,12
  for (int k0 = 0; k0 < K; k0 += 16) {
    float4 a4 = *(const float4*)(A + (size_t)(bm + ar) * lda + k0 + ac);
    As[ac+0][ar] = a4.x; As[ac+1][ar] = a4.y; As[ac+2][ar] = a4.z; As[ac+3][ar] = a4.w;
    if (!TRANSB) {
      int br  = tid >> 4;          // 0..15 (k)
      int bcc = (tid & 15) << 2;   // n
      float4 b4 = *(const float4*)(Bm + (size_t)(k0 + br) * ldb + bn + bcc);
      *(float4*)&Bs[br][bcc] = b4;
    } else {
      int bn_ = tid >> 2;          // 0..63 (n)
      int bk  = (tid & 3) << 2;    // k
      float4 b4 = *(const float4*)(Bm + (size_t)(bn + bn_) * ldb + k0 + bk);
      Bs[bk+0][bn_] = b4.x; Bs[bk+1][bn_] = b4.y; Bs[bk+2][bn_] = b4.z; Bs[bk+3][bn_] = b4.w;
    }
    __syncthreads();
    #pragma unroll
    for (int kk = 0; kk < 16; ++kk) {
      float4 av = *(const float4*)&As[kk][ty << 2];
      float4 bv = *(const float4*)&Bs[kk][tx << 2];
      acc[0][0] += av.x*bv.x; acc[0][1] += av.x*bv.y; acc[0][2] += av.x*bv.z; acc[0][3] += av.x*bv.w;
      acc[1][0] += av.y*bv.x; acc[1][1] += av.y*bv.y; acc[1][2] += av.y*bv.z; acc[1][3] += av.y*bv.w;
      acc[2][0] += av.z*bv.x; acc[2][1] += av.z*bv.y; acc[2][2] += av.z*bv.z; acc[2][3] += av.z*bv.w;
      acc[3][0] += av.w*bv.x; acc[3][1] += av.w*bv.y; acc[3][2] += av.w*bv.z; acc[3][3] += av.w*bv.w;
    }
    __syncthreads();
  }
  #pragma unroll
  for (int ii = 0; ii < 4; ++ii) {
    int row = bm + (ty << 2) + ii;
    #pragma unroll
    for (int jj = 0; jj < 4; ++jj) {
      int col = bn + (tx << 2) + jj;
      float val = acc[ii][jj];
      if (bias) val += bias[col];
      if (GELU_) val = gelu_f(val);
      if (res)  val += res[(size_t)row * ldc + col];
      C[(size_t)row * ldc + col] = val;
    }
  }
}

// ---------------- add q/k head into Pq/Pk (qa = q_head + Pq, in place) -----
__global__ __launch_bounds__(256) void addhead_kernel(
    const float* __restrict__ q, const float* __restrict__ k,
    float* __restrict__ Pq, float* __restrict__ Pk)
{
  int idx = blockIdx.x * 256 + threadIdx.x;   // < LA*BT*DK = 262144
  int dk = idx & 127;
  int rest = idx >> 7;        // a*1024 + m
  int m = rest & 1023;
  int a = rest >> 10;
  Pq[idx] += q[(size_t)m * Dc + a * DKc + dk];
  Pk[idx] += k[(size_t)m * Dc + a * DKc + dk];
}

// ---------------- uin = Xq + rel_bias ; cvec = brk . uin -------------------
__global__ __launch_bounds__(128) void uin_kernel(
    const float* __restrict__ q, const float* __restrict__ rel_bias,
    const float* __restrict__ brk, float* __restrict__ uin,
    float* __restrict__ cvec)
{
  int blk = blockIdx.x;      // l*1024 + m
  int tid = threadIdx.x;     // 0..127
  int l = blk >> 10;
  float val = q[(size_t)(blk & 1023) * Dc + (LAc + l) * DKc + tid] + rel_bias[l * DKc + tid];
  uin[(size_t)blk * DKc + tid] = val;
  __shared__ float red[128];
  red[tid] = brk[l * DKc + tid] * val;
  __syncthreads();
  #pragma unroll
  for (int off = 64; off > 0; off >>= 1) {
    if (tid < off) red[tid] += red[tid + off];
    __syncthreads();
  }
  if (tid == 0) cvec[blk] = red[0];
}

// ---------------- THE streaming kernel: rel_dot over 537 MB ---------------
// block = (l*B + b)*T + i ; each of 4 waves handles 32 j rows of 512 floats.
__global__ __launch_bounds__(256) void reldot_kernel(
    const float* __restrict__ rk, const float* __restrict__ u,
    float* __restrict__ scores)
{
  int blk = blockIdx.x;               // l*1024 + b*128 + i
  int tid = threadIdx.x;
  int wave = tid >> 6, lane = tid & 63;
  const float* ur = u + (size_t)blk * Dc + lane * 8;
  float4 uu0 = *(const float4*)ur;
  float4 uu1 = *(const float4*)(ur + 4);
  const float* base = rk + (size_t)blk * (Tc * Dc);
  int i = blk & 127, b = (blk >> 7) & 7, l = blk >> 10;
  float* srow = scores + (((size_t)(b * Hc + LAc + l) * Tc + i) * Tc);
  #pragma unroll 2
  for (int jj = 0; jj < 32; ++jj) {
    int j = (wave << 5) + jj;
    const float* r = base + (size_t)j * Dc + lane * 8;
    float4 r0 = *(const float4*)r;
    float4 r1 = *(const float4*)(r + 4);
    float s = r0.x*uu0.x + r0.y*uu0.y + r0.z*uu0.z + r0.w*uu0.w
            + r1.x*uu1.x + r1.y*uu1.y + r1.z*uu1.z + r1.w*uu1.w;
    #pragma unroll
    for (int off = 32; off > 0; off >>= 1) s += __shfl_xor(s, off);
    if (lane == 0) srow[j] = s;
  }
}

// ---------------- attention: scores -> softmax -> @v, per (b,h,i) ----------
__global__ __launch_bounds__(128) void attn_kernel(
    const float* __restrict__ q, const float* __restrict__ k,
    const float* __restrict__ v, const float* __restrict__ qa,
    const float* __restrict__ ka, const float* __restrict__ scores,
    const float* __restrict__ cvec, const int* __restrict__ mask,
    float* __restrict__ attnout)
{
  int blk = blockIdx.x;            // (b*H + h)*T + i
  int tid = threadIdx.x;           // 0..127
  int i = blk & 127;
  int bh = blk >> 7;
  int h = bh & 3;
  int b = bh >> 2;
  __shared__ float qs[128];
  __shared__ float ps[128];
  __shared__ float red[128];
  int m_i = b * Tc + i;
  const float* qrow = (h < LAc) ? (qa + ((size_t)h * BTc + m_i) * DKc)
                                : (q + (size_t)m_i * Dc + h * DKc);
  qs[tid] = qrow[tid];
  __syncthreads();
  int j = tid;
  int m_j = b * Tc + j;
  const float* krow;
  float s0;
  if (h < LAc) {
    krow = ka + ((size_t)h * BTc + m_j) * DKc;
    s0 = 0.0f;
  } else {
    krow = k + (size_t)m_j * Dc + h * DKc;
    s0 = scores[(size_t)blk * Tc + j] + cvec[(h - LAc) * BTc + m_i];
  }
  float dot = 0.0f;
  #pragma unroll
  for (int d = 0; d < 128; d += 4) {
    float4 kv = *(const float4*)(krow + d);
    dot += kv.x*qs[d] + kv.y*qs[d+1] + kv.z*qs[d+2] + kv.w*qs[d+3];
  }
  float s = (s0 + dot) * 0.088388347648318447f;
  if (mask[((size_t)b * Tc + i) * Tc + j] == 0) s = -1e9f;
  red[tid] = s;
  __syncthreads();
  #pragma unroll
  for (int off = 64; off > 0; off >>= 1) {
    if (tid < off) red[tid] = fmaxf(red[tid], red[tid + off]);
    __syncthreads();
  }
  float mx = red[0];
  __syncthreads();
  float e = expf(s - mx);
  ps[tid] = e;
  red[tid] = e;
  __syncthreads();
  #pragma unroll
  for (int off = 64; off > 0; off >>= 1) {
    if (tid < off) red[tid] += red[tid + off];
    __syncthreads();
  }
  float inv = 1.0f / red[0];
  // p @ v : thread owns output dk
  int dk = tid;
  const float* vp = v + (size_t)b * Tc * Dc + h * DKc + dk;
  float o = 0.0f;
  for (int jj = 0; jj < 128; ++jj) o += ps[jj] * vp[(size_t)jj * Dc];
  attnout[(size_t)m_i * Dc + h * DKc + dk] = o * inv;
}

// ---------------------------------------------------------------------------
extern "C" void kernel_launch(void* const* d_in, const int* in_sizes, int n_in,
                              void* d_out, int out_size, void* d_ws, size_t ws_size,
                              hipStream_t stream)
{
  const float* x         = (const float*)d_in[0];
  const int*   mask      = (const int*)  d_in[1];
  const float* abs_kernel= (const float*)d_in[2];
  const float* rel_kernel= (const float*)d_in[3];
  const float* Wc        = (const float*)d_in[4];
  const float* bc        = (const float*)d_in[5];
  const float* Wpq       = (const float*)d_in[6];
  const float* bpq       = (const float*)d_in[7];
  const float* Wpk       = (const float*)d_in[8];
  const float* bpk       = (const float*)d_in[9];
  const float* Wrk       = (const float*)d_in[10];
  const float* brk       = (const float*)d_in[11];
  const float* rel_bias  = (const float*)d_in[12];
  const float* Wo        = (const float*)d_in[13];
  const float* bo        = (const float*)d_in[14];
  const float* W1        = (const float*)d_in[15];
  const float* b1        = (const float*)d_in[16];
  const float* W2        = (const float*)d_in[17];
  const float* b2        = (const float*)d_in[18];
  const float* ln1g      = (const float*)d_in[19];
  const float* ln1b      = (const float*)d_in[20];
  const float* ln2g      = (const float*)d_in[21];
  const float* ln2b      = (const float*)d_in[22];

  float* ws = (float*)d_ws;
  float* h      = ws + 0;         // 524288  (reused for h2)
  float* q      = ws + 524288;    // 524288  (reused by f1)
  float* k      = ws + 1048576;   // 524288
  float* v      = ws + 1572864;   // 524288
  float* Pq     = ws + 2097152;   // 262144  (becomes qa)
  float* Pk     = ws + 2359296;   // 262144  (becomes ka)
  float* uin    = ws + 2621440;   // 262144
  float* u      = ws + 2883584;   // 1048576
  float* cvec   = ws + 3932160;   // 2048
  float* scores = ws + 3934208;   // 524288
  float* attnout= ws + 4458496;   // 524288
  float* x1     = ws + 4982784;   // 524288
  float* f1     = q;              // 2097152, overlays q..Pk (dead by then)
  float* h2     = h;
  float* out    = (float*)d_out;

  // 1. LN1
  ln_kernel<<<256, 256, 0, stream>>>(x, ln1g, ln1b, h, BTc);

  // 2. qkv projections (layout (B,T,H*DK))
  dim3 blk256(256);
  dim3 g512(512/64, BTc/64);
  gemm_kernel<false,false><<<g512, blk256, 0, stream>>>(h, Dc, Wc + 0*Dc*Dc, Dc, bc + 0*Dc, nullptr, q, Dc, BTc, Dc, Dc);
  gemm_kernel<false,false><<<g512, blk256, 0, stream>>>(h, Dc, Wc + 1*Dc*Dc, Dc, bc + 1*Dc, nullptr, k, Dc, BTc, Dc, Dc);
  gemm_kernel<false,false><<<g512, blk256, 0, stream>>>(h, Dc, Wc + 2*Dc*Dc, Dc, bc + 2*Dc, nullptr, v, Dc, BTc, Dc, Dc);

  // 3. Pq/Pk projections per abs layer
  dim3 g128(128/64, BTc/64);
  for (int a = 0; a < LAc; ++a) {
    gemm_kernel<false,false><<<g128, blk256, 0, stream>>>(abs_kernel + (size_t)a*BTc*Dc, Dc,
        Wpq + (size_t)a*Dc*DKc, DKc, bpq + a*DKc, nullptr, Pq + (size_t)a*BTc*DKc, DKc, BTc, DKc, Dc);
    gemm_kernel<false,false><<<g128, blk256, 0, stream>>>(abs_kernel + (size_t)a*BTc*Dc, Dc,
        Wpk + (size_t)a*Dc*DKc, DKc, bpk + a*DKc, nullptr, Pk + (size_t)a*BTc*DKc, DKc, BTc, DKc, Dc);
  }

  // 4. qa = q_head + Pq ; ka = k_head + Pk (in place)
  addhead_kernel<<<(LAc*BTc*DKc)/256, blk256, 0, stream>>>(q, k, Pq, Pk);

  // 5. uin = Xq + rel_bias, cvec = brk . uin
  uin_kernel<<<LRc*BTc, 128, 0, stream>>>(q, rel_bias, brk, uin, cvec);

  // 6. u = uin @ Wrk^T per rel layer
  dim3 gu(512/64, BTc/64);
  for (int l = 0; l < LRc; ++l) {
    gemm_kernel<true,false><<<gu, blk256, 0, stream>>>(uin + (size_t)l*BTc*DKc, DKc,
        Wrk + (size_t)l*Dc*DKc, DKc, nullptr, nullptr, u + (size_t)l*BTc*Dc, Dc, BTc, Dc, DKc);
  }

  // 7. rel_dot: the 537 MB stream (writes rel slots of scores)
  reldot_kernel<<<LRc*BTc, blk256, 0, stream>>>(rel_kernel, u, scores);

  // 8. attention: scores -> softmax -> @v
  attn_kernel<<<Bc*Hc*Tc, 128, 0, stream>>>(q, k, v, Pq, Pk, scores, cvec, mask, attnout);

  // 9. output projection + residual: x1 = attnout @ Wo + bo + x
  gemm_kernel<false,false><<<g512, blk256, 0, stream>>>(attnout, Dc, Wo, Dc, bo, x, x1, Dc, BTc, Dc, Dc);

  // 10. LN2
  ln_kernel<<<256, 256, 0, stream>>>(x1, ln2g, ln2b, h2, BTc);

  // 11. FFN1 + GELU
  dim3 gf1(DFFc/64, BTc/64);
  gemm_kernel<false,true><<<gf1, blk256, 0, stream>>>(h2, Dc, W1, DFFc, b1, nullptr, f1, DFFc, BTc, DFFc, Dc);

  // 12. FFN2 + residual -> out
  gemm_kernel<false,false><<<g512, blk256, 0, stream>>>(f1, DFFc, W2, Dc, b2, x1, out, Dc, BTc, Dc, DFFc);
}

// Round 2
// 480.535 us; speedup vs baseline: 1.4121x; 1.4121x over previous
//
#include <hip/hip_runtime.h>
#include <math.h>

static constexpr int Bc  = 8;
static constexpr int Tc  = 128;
static constexpr int Dc  = 512;
static constexpr int LAc = 2;
static constexpr int Hc  = 4;
static constexpr int DKc = 128;
static constexpr int BTc = 1024;   // B*T

typedef __attribute__((ext_vector_type(8))) short short8v;
typedef __attribute__((ext_vector_type(4))) float f32x4;

static __device__ __forceinline__ ushort f2bf(float x) {
  unsigned u = __builtin_bit_cast(unsigned, x);
  unsigned r = (u + 0x7fffu + ((u >> 16) & 1u)) >> 16;
  return (ushort)r;
}

__device__ __forceinline__ float gelu_f(float v) {
  float t = tanhf(0.7978845608028654f * (v + 0.044715f * v * v * v));
  return 0.5f * v * (1.0f + t);
}

// ---------------- LayerNorm: one wave per 512-row, bf16 out ----------------
__global__ __launch_bounds__(256) void ln_kernel(const float* __restrict__ x,
    const float* __restrict__ g, const float* __restrict__ bb,
    ushort* __restrict__ out)
{
  int gid = blockIdx.x * 256 + threadIdx.x;
  int row = gid >> 6;
  int lane = threadIdx.x & 63;
  const float* xr = x + (size_t)row * Dc + lane * 8;
  float4 a = *(const float4*)xr;
  float4 c = *(const float4*)(xr + 4);
  float s  = a.x + a.y + a.z + a.w + c.x + c.y + c.z + c.w;
  float ss = a.x*a.x + a.y*a.y + a.z*a.z + a.w*a.w
           + c.x*c.x + c.y*c.y + c.z*c.z + c.w*c.w;
  #pragma unroll
  for (int off = 32; off > 0; off >>= 1) {
    s  += __shfl_xor(s, off);
    ss += __shfl_xor(ss, off);
  }
  float mu  = s * (1.0f/512.0f);
  float var = ss * (1.0f/512.0f) - mu*mu;
  float rstd = rsqrtf(var + 1e-5f);
  const float* gp = g + lane*8;
  const float* bp = bb + lane*8;
  float4 g0 = *(const float4*)gp, g1 = *(const float4*)(gp+4);
  float4 b0 = *(const float4*)bp, b1 = *(const float4*)(bp+4);
  union { ushort u[8]; uint4 v; } pk;
  pk.u[0] = f2bf((a.x-mu)*rstd*g0.x + b0.x);
  pk.u[1] = f2bf((a.y-mu)*rstd*g0.y + b0.y);
  pk.u[2] = f2bf((a.z-mu)*rstd*g0.z + b0.z);
  pk.u[3] = f2bf((a.w-mu)*rstd*g0.w + b0.w);
  pk.u[4] = f2bf((c.x-mu)*rstd*g1.x + b1.x);
  pk.u[5] = f2bf((c.y-mu)*rstd*g1.y + b1.y);
  pk.u[6] = f2bf((c.z-mu)*rstd*g1.z + b1.z);
  pk.u[7] = f2bf((c.w-mu)*rstd*g1.w + b1.w);
  *(uint4*)(out + (size_t)row * Dc + lane * 8) = pk.v;
}

// ---------------- convert / transpose weights to bf16 ---------------------
struct CvtTasks {
  const float* src[16];
  void* dst[16];
  int rows[16], cols[16], mode[16], aux[16], end[16];
  int n;
};

__global__ __launch_bounds__(256) void cvt_kernel(CvtTasks T)
{
  __shared__ ushort tile[64][65];
  int b = blockIdx.x, t = threadIdx.x;
  int ti = 0;
  while (b >= T.end[ti]) ++ti;
  int lb = b - (ti ? T.end[ti-1] : 0);
  const float* src = T.src[ti];
  int mode = T.mode[ti];
  if (mode == 0) {
    // transpose R x C (f32) -> C x R (bf16)
    int R = T.rows[ti], C = T.cols[ti];
    int tpr = C >> 6;
    int tyy = lb / tpr, txx = lb - tyy * tpr;
    int r0 = tyy << 6, c0 = txx << 6;
    int lr = t >> 4, lc4 = (t & 15) << 2;
    #pragma unroll
    for (int i = 0; i < 4; ++i) {
      int row = i*16 + lr;
      float4 vv = *(const float4*)(src + (size_t)(r0+row)*C + c0 + lc4);
      tile[row][lc4+0] = f2bf(vv.x);
      tile[row][lc4+1] = f2bf(vv.y);
      tile[row][lc4+2] = f2bf(vv.z);
      tile[row][lc4+3] = f2bf(vv.w);
    }
    __syncthreads();
    ushort* dst = (ushort*)T.dst[ti];
    #pragma unroll
    for (int i = 0; i < 4; ++i) {
      int n = i*16 + lr;
      ushort4 o;
      o.x = tile[lc4+0][n];
      o.y = tile[lc4+1][n];
      o.z = tile[lc4+2][n];
      o.w = tile[lc4+3][n];
      *(ushort4*)(dst + (size_t)(c0+n)*R + r0 + lc4) = o;
    }
  } else if (mode == 1) {
    // plain convert, rows = total elems (multiple of 2048)
    int idx = lb*2048 + t*8;
    float4 v0 = *(const float4*)(src + idx);
    float4 v1 = *(const float4*)(src + idx + 4);
    union { ushort u[8]; uint4 q; } pk;
    pk.u[0]=f2bf(v0.x); pk.u[1]=f2bf(v0.y); pk.u[2]=f2bf(v0.z); pk.u[3]=f2bf(v0.w);
    pk.u[4]=f2bf(v1.x); pk.u[5]=f2bf(v1.y); pk.u[6]=f2bf(v1.z); pk.u[7]=f2bf(v1.w);
    *(uint4*)((ushort*)T.dst[ti] + idx) = pk.q;
  } else {
    // bias interleave: dst[(2r+aux)*cols + t] = src[r*cols + t]
    if (t < T.cols[ti]) {
      float* d = (float*)T.dst[ti];
      for (int r = 0; r < T.rows[ti]; ++r)
        d[(size_t)(2*r + T.aux[ti]) * T.cols[ti] + t] = src[(size_t)r * T.cols[ti] + t];
    }
  }
}

// ---------------- MFMA bf16 GEMM: C = A(MxK) * Bt(NxK)^T ------------------
// 128x128 tile, BK=64, 256 threads = 4 waves (2x2), 64x64 per wave.
// LDS rows 128B with XOR swizzle byte ^= (row&7)<<4 (T2).
template<bool OUT_BF16, bool GELU_, bool RES_>
__global__ __launch_bounds__(256) void mfma_gemm(
    const ushort* __restrict__ A, int lda, long Abatch, int adiv,
    const ushort* __restrict__ Bt, int ldb, long Bbatch,
    const float* __restrict__ bias, int biasStride,
    const float* __restrict__ res,
    void* __restrict__ Cout, int ldc, long Cbatch,
    int K)
{
  __shared__ __align__(16) char smem[32768];
  char* asB = smem;
  char* bsB = smem + 16384;
  int tid = threadIdx.x;
  int lane = tid & 63, wid = tid >> 6;
  int wr = wid >> 1, wc = wid & 1;
  int z = blockIdx.z;
  int bm = blockIdx.y * 128, bn = blockIdx.x * 128;
  const ushort* Ab = A + (size_t)(z / adiv) * Abatch + (size_t)bm * lda;
  const ushort* Bb = Bt + (size_t)z * Bbatch + (size_t)bn * ldb;

  f32x4 acc[4][4] = {};

  int l15 = lane & 15, kg = lane >> 4;
  int frA = wr*64 + l15;
  int frB = wc*64 + l15;

  int srow[4], spc[4];
  #pragma unroll
  for (int i = 0; i < 4; ++i) { int g = i*256 + tid; srow[i] = g >> 3; spc[i] = g & 7; }

  for (int k0 = 0; k0 < K; k0 += 64) {
    uint4 ra[4], rb[4];
    #pragma unroll
    for (int i = 0; i < 4; ++i) {
      ra[i] = *(const uint4*)(Ab + (size_t)srow[i]*lda + k0 + spc[i]*8);
      rb[i] = *(const uint4*)(Bb + (size_t)srow[i]*ldb + k0 + spc[i]*8);
    }
    __syncthreads();   // prior ds_reads complete before overwrite
    #pragma unroll
    for (int i = 0; i < 4; ++i) {
      int wbyte = srow[i]*128 + ((spc[i]*16) ^ ((srow[i]&7)<<4));
      *(uint4*)(asB + wbyte) = ra[i];
      *(uint4*)(bsB + wbyte) = rb[i];
    }
    __syncthreads();
    #pragma unroll
    for (int ks = 0; ks < 2; ++ks) {
      short8v av[4], bv[4];
      int cb = ks*64 + kg*16;
      #pragma unroll
      for (int m = 0; m < 4; ++m) {
        int r = frA + m*16;
        av[m] = *(const short8v*)(asB + r*128 + (cb ^ ((r&7)<<4)));
      }
      #pragma unroll
      for (int n = 0; n < 4; ++n) {
        int r = frB + n*16;
        bv[n] = *(const short8v*)(bsB + r*128 + (cb ^ ((r&7)<<4)));
      }
      #pragma unroll
      for (int m = 0; m < 4; ++m)
        #pragma unroll
        for (int n = 0; n < 4; ++n)
          acc[m][n] = __builtin_amdgcn_mfma_f32_16x16x32_bf16(av[m], bv[n], acc[m][n], 0, 0, 0);
    }
  }

  int orow0 = bm + wr*64 + kg*4;
  int ocol0 = bn + wc*64 + l15;
  const float* bz = bias ? (bias + (size_t)z * biasStride) : nullptr;
  size_t cb0 = (size_t)z * Cbatch;
  #pragma unroll
  for (int m = 0; m < 4; ++m) {
    #pragma unroll
    for (int r = 0; r < 4; ++r) {
      int row = orow0 + m*16 + r;
      #pragma unroll
      for (int n = 0; n < 4; ++n) {
        int col = ocol0 + n*16;
        float val = acc[m][n][r];
        if (bz) val += bz[col];
        if (GELU_) val = gelu_f(val);
        if (RES_) val += res[(size_t)row*ldc + col];
        if (OUT_BF16) ((ushort*)Cout)[cb0 + (size_t)row*ldc + col] = f2bf(val);
        else          ((float*)Cout)[cb0 + (size_t)row*ldc + col] = val;
      }
    }
  }
}

// ---------------- qa/ka = heads + positional projections (in place) -------
__global__ __launch_bounds__(256) void addhead_kernel(
    const float* __restrict__ q, const float* __restrict__ k,
    float* __restrict__ Pqk)
{
  int idx = blockIdx.x * 256 + threadIdx.x;   // < LA*BT*DK = 262144
  int dk = idx & 127;
  int rest = idx >> 7;
  int m = rest & 1023;
  int a = rest >> 10;
  Pqk[idx + a*131072]     += q[(size_t)m * Dc + a * DKc + dk];
  Pqk[idx + (a+1)*131072] += k[(size_t)m * Dc + a * DKc + dk];
}

// ---------------- uin = Xq + rel_bias (bf16) ; cvec = brk . uin ------------
__global__ __launch_bounds__(128) void uin_kernel(
    const float* __restrict__ q, const float* __restrict__ rel_bias,
    const float* __restrict__ brk, ushort* __restrict__ uinb,
    float* __restrict__ cvec)
{
  int blk = blockIdx.x;      // l*1024 + m
  int tid = threadIdx.x;     // 0..127
  int l = blk >> 10;
  float val = q[(size_t)(blk & 1023) * Dc + (LAc + l) * DKc + tid] + rel_bias[l * DKc + tid];
  uinb[(size_t)blk * DKc + tid] = f2bf(val);
  __shared__ float red[128];
  red[tid] = brk[l * DKc + tid] * val;
  __syncthreads();
  #pragma unroll
  for (int off = 64; off > 0; off >>= 1) {
    if (tid < off) red[tid] += red[tid + off];
    __syncthreads();
  }
  if (tid == 0) cvec[blk] = red[0];
}

// ---------------- streaming rel_dot over 537 MB ---------------------------
__global__ __launch_bounds__(256) void reldot_kernel(
    const float* __restrict__ rk, const float* __restrict__ u,
    float* __restrict__ scores)
{
  int blk = blockIdx.x;               // l*1024 + b*128 + i
  int tid = threadIdx.x;
  int wave = tid >> 6, lane = tid & 63;
  const float* ur = u + (size_t)blk * Dc + lane * 8;
  float4 uu0 = *(const float4*)ur;
  float4 uu1 = *(const float4*)(ur + 4);
  const float* base = rk + (size_t)blk * (Tc * Dc);
  int i = blk & 127, b = (blk >> 7) & 7, l = blk >> 10;
  float* srow = scores + (((size_t)(b * Hc + LAc + l) * Tc + i) * Tc);
  #pragma unroll 2
  for (int jj = 0; jj < 32; ++jj) {
    int j = (wave << 5) + jj;
    const float* r = base + (size_t)j * Dc + lane * 8;
    float4 r0 = *(const float4*)r;
    float4 r1 = *(const float4*)(r + 4);
    float s = r0.x*uu0.x + r0.y*uu0.y + r0.z*uu0.z + r0.w*uu0.w
            + r1.x*uu1.x + r1.y*uu1.y + r1.z*uu1.z + r1.w*uu1.w;
    #pragma unroll
    for (int off = 32; off > 0; off >>= 1) s += __shfl_xor(s, off);
    if (lane == 0) srow[j] = s;
  }
}

// ---------------- attention: scores -> softmax -> @v ----------------------
__global__ __launch_bounds__(128) void attn_kernel(
    const float* __restrict__ q, const float* __restrict__ k,
    const float* __restrict__ v, const float* __restrict__ Pqk,
    const float* __restrict__ scores, const float* __restrict__ cvec,
    const int* __restrict__ mask, ushort* __restrict__ attnob)
{
  int blk = blockIdx.x;            // (b*H + h)*T + i
  int tid = threadIdx.x;           // 0..127
  int i = blk & 127;
  int bh = blk >> 7;
  int h = bh & 3;
  int b = bh >> 2;
  __shared__ float qs[128];
  __shared__ float ps[128];
  __shared__ float red[128];
  int m_i = b * Tc + i;
  const float* qrow = (h < LAc) ? (Pqk + (size_t)(2*h) * 131072 + (size_t)m_i * DKc)
                                : (q + (size_t)m_i * Dc + h * DKc);
  qs[tid] = qrow[tid];
  __syncthreads();
  int j = tid;
  int m_j = b * Tc + j;
  const float* krow;
  float s0;
  if (h < LAc) {
    krow = Pqk + (size_t)(2*h+1) * 131072 + (size_t)m_j * DKc;
    s0 = 0.0f;
  } else {
    krow = k + (size_t)m_j * Dc + h * DKc;
    s0 = scores[(size_t)blk * Tc + j] + cvec[(h - LAc) * BTc + m_i];
  }
  float dot = 0.0f;
  #pragma unroll
  for (int d = 0; d < 128; d += 4) {
    float4 kv = *(const float4*)(krow + d);
    dot += kv.x*qs[d] + kv.y*qs[d+1] + kv.z*qs[d+2] + kv.w*qs[d+3];
  }
  float s = (s0 + dot) * 0.088388347648318447f;
  if (mask[((size_t)b * Tc + i) * Tc + j] == 0) s = -1e9f;
  red[tid] = s;
  __syncthreads();
  #pragma unroll
  for (int off = 64; off > 0; off >>= 1) {
    if (tid < off) red[tid] = fmaxf(red[tid], red[tid + off]);
    __syncthreads();
  }
  float mx = red[0];
  __syncthreads();
  float e = expf(s - mx);
  ps[tid] = e;
  red[tid] = e;
  __syncthreads();
  #pragma unroll
  for (int off = 64; off > 0; off >>= 1) {
    if (tid < off) red[tid] += red[tid + off];
    __syncthreads();
  }
  float inv = 1.0f / red[0];
  int dk = tid;
  const float* vp = v + (size_t)b * Tc * Dc + h * DKc + dk;
  float o = 0.0f;
  for (int jj = 0; jj < 128; ++jj) o += ps[jj] * vp[(size_t)jj * Dc];
  attnob[(size_t)m_i * Dc + h * DKc + dk] = f2bf(o * inv);
}

// ---------------------------------------------------------------------------
extern "C" void kernel_launch(void* const* d_in, const int* in_sizes, int n_in,
                              void* d_out, int out_size, void* d_ws, size_t ws_size,
                              hipStream_t stream)
{
  const float* x         = (const float*)d_in[0];
  const int*   mask      = (const int*)  d_in[1];
  const float* abs_kernel= (const float*)d_in[2];
  const float* rel_kernel= (const float*)d_in[3];
  const float* Wc        = (const float*)d_in[4];
  const float* bc        = (const float*)d_in[5];
  const float* Wpq       = (const float*)d_in[6];
  const float* bpq       = (const float*)d_in[7];
  const float* Wpk       = (const float*)d_in[8];
  const float* bpk       = (const float*)d_in[9];
  const float* Wrk       = (const float*)d_in[10];
  const float* brk       = (const float*)d_in[11];
  const float* rel_bias  = (const float*)d_in[12];
  const float* Wo        = (const float*)d_in[13];
  const float* bo        = (const float*)d_in[14];
  const float* W1        = (const float*)d_in[15];
  const float* b1        = (const float*)d_in[16];
  const float* W2        = (const float*)d_in[17];
  const float* b2        = (const float*)d_in[18];
  const float* ln1g      = (const float*)d_in[19];
  const float* ln1b      = (const float*)d_in[20];
  const float* ln2g      = (const float*)d_in[21];
  const float* ln2b      = (const float*)d_in[22];

  float* ws = (float*)d_ws;
  float* q      = ws;               // 524288
  float* kbuf   = ws + 524288;      // 524288
  float* v      = ws + 1048576;     // 524288
  float* Pqk    = ws + 1572864;     // 524288 (4 x 1024 x 128, z = a*2+{q,k})
  float* u      = ws + 2097152;     // 1048576
  float* scores = ws + 3145728;     // 524288
  float* x1     = ws + 3670016;     // 524288
  float* cvec   = ws + 4194304;     // 2048
  float* bqk    = ws + 4196352;     // 512 packed (bpq/bpk interleaved)
  ushort* bf    = (ushort*)(ws + 4196864);
  ushort* h     = bf;               // 524288
  ushort* h2    = bf + 524288;      // 524288
  ushort* uinb  = bf + 1048576;     // 262144
  ushort* attnob= bf + 1310720;     // 524288
  ushort* f1    = bf + 1835008;     // 2097152
  ushort* absb  = bf + 3932160;     // 1048576
  ushort* WcT   = bf + 4980736;     // 786432
  ushort* Wp    = bf + 5767168;     // 262144 (4 x 128 x 512)
  ushort* Wrkb  = bf + 6029312;     // 131072 (2 x 512 x 128, native layout = Bt)
  ushort* WoT   = bf + 6160384;     // 262144
  ushort* W1T   = bf + 6422528;     // 1048576
  ushort* W2T   = bf + 7471104;     // 1048576
  float* out    = (float*)d_out;

  // ---- build convert/transpose task table ----
  CvtTasks T{};
  int nb = 0, ti = 0;
  auto addTr = [&](const float* s, ushort* d, int R, int C) {
    T.src[ti]=s; T.dst[ti]=d; T.rows[ti]=R; T.cols[ti]=C; T.mode[ti]=0; T.aux[ti]=0;
    nb += (R/64)*(C/64); T.end[ti]=nb; ++ti;
  };
  auto addCv = [&](const float* s, ushort* d, int n) {
    T.src[ti]=s; T.dst[ti]=d; T.rows[ti]=n; T.cols[ti]=0; T.mode[ti]=1; T.aux[ti]=0;
    nb += n/2048; T.end[ti]=nb; ++ti;
  };
  auto addBi = [&](const float* s, float* d, int aux) {
    T.src[ti]=s; T.dst[ti]=d; T.rows[ti]=2; T.cols[ti]=128; T.mode[ti]=2; T.aux[ti]=aux;
    nb += 1; T.end[ti]=nb; ++ti;
  };
  for (int c = 0; c < 3; ++c) addTr(Wc + (size_t)c*262144, WcT + (size_t)c*262144, 512, 512);
  addTr(Wo, WoT, 512, 512);
  addTr(W1, W1T, 512, 2048);
  addTr(W2, W2T, 2048, 512);
  for (int a = 0; a < 2; ++a) addTr(Wpq + (size_t)a*65536, Wp + (size_t)(2*a)*65536, 512, 128);
  for (int a = 0; a < 2; ++a) addTr(Wpk + (size_t)a*65536, Wp + (size_t)(2*a+1)*65536, 512, 128);
  addCv(abs_kernel, absb, 1048576);
  addCv(Wrk, Wrkb, 131072);
  addBi(bpq, bqk, 0);
  addBi(bpk, bqk, 1);
  T.n = ti;

  cvt_kernel<<<nb, 256, 0, stream>>>(T);

  // LN1 -> h (bf16)
  ln_kernel<<<256, 256, 0, stream>>>(x, ln1g, ln1b, h);

  // qkv: z=3 batched, C = q|k|v contiguous (fp32)
  mfma_gemm<false,false,false><<<dim3(4,8,3), 256, 0, stream>>>(
      h, 512, 0, 1, WcT, 512, 262144, bc, 512, nullptr, q, 512, 524288, 512);

  // Pqk: z=4 batched (a0q,a0k,a1q,a1k)
  mfma_gemm<false,false,false><<<dim3(1,8,4), 256, 0, stream>>>(
      absb, 512, 524288, 2, Wp, 512, 65536, bqk, 128, nullptr, Pqk, 128, 131072, 512);

  // qa/ka accumulate
  addhead_kernel<<<1024, 256, 0, stream>>>(q, kbuf, Pqk);

  // uin (bf16) + cvec
  uin_kernel<<<2048, 128, 0, stream>>>(q, rel_bias, brk, uinb, cvec);

  // u = uin @ Wrk^T (Bt = Wrk native layout), z=2
  mfma_gemm<false,false,false><<<dim3(4,8,2), 256, 0, stream>>>(
      uinb, 128, 131072, 1, Wrkb, 128, 65536, nullptr, 0, nullptr, u, 512, 524288, 128);

  // rel_dot stream
  reldot_kernel<<<2048, 256, 0, stream>>>(rel_kernel, u, scores);

  // attention
  attn_kernel<<<4096, 128, 0, stream>>>(q, kbuf, v, Pqk, scores, cvec, mask, attnob);

  // out-proj + residual(x) -> x1 (fp32)
  mfma_gemm<false,false,true><<<dim3(4,8,1), 256, 0, stream>>>(
      attnob, 512, 0, 1, WoT, 512, 0, bo, 0, x, x1, 512, 0, 512);

  // LN2 -> h2 (bf16)
  ln_kernel<<<256, 256, 0, stream>>>(x1, ln2g, ln2b, h2);

  // FFN1 + GELU -> f1 (bf16)
  mfma_gemm<true,true,false><<<dim3(16,8,1), 256, 0, stream>>>(
      h2, 512, 0, 1, W1T, 512, 0, b1, 0, nullptr, f1, 2048, 0, 512);

  // FFN2 + residual(x1) -> out (fp32)
  mfma_gemm<false,false,true><<<dim3(4,8,1), 256, 0, stream>>>(
      f1, 2048, 0, 1, W2T, 2048, 0, b2, 0, x1, out, 512, 0, 2048);
}

// Round 3
// 217.823 us; speedup vs baseline: 3.1151x; 2.2061x over previous
//
#include <hip/hip_runtime.h>
#include <math.h>

static constexpr int Dc  = 512;
static constexpr int DKc = 128;

typedef __attribute__((ext_vector_type(8))) short short8v;
typedef __attribute__((ext_vector_type(4))) float f32x4;

static __device__ __forceinline__ ushort f2bf(float x) {
  unsigned u = __builtin_bit_cast(unsigned, x);
  unsigned r = (u + 0x7fffu + ((u >> 16) & 1u)) >> 16;
  return (ushort)r;
}

__device__ __forceinline__ float gelu_f(float v) {
  float t = tanhf(0.7978845608028654f * (v + 0.044715f * v * v * v));
  return 0.5f * v * (1.0f + t);
}

// ---------------- LayerNorm: one wave per 512-row, bf16 out ----------------
__global__ __launch_bounds__(256) void ln_kernel(const float* __restrict__ x,
    const float* __restrict__ g, const float* __restrict__ bb,
    ushort* __restrict__ out)
{
  int gid = blockIdx.x * 256 + threadIdx.x;
  int row = gid >> 6;
  int lane = threadIdx.x & 63;
  const float* xr = x + (size_t)row * Dc + lane * 8;
  float4 a = *(const float4*)xr;
  float4 c = *(const float4*)(xr + 4);
  float s  = a.x + a.y + a.z + a.w + c.x + c.y + c.z + c.w;
  float ss = a.x*a.x + a.y*a.y + a.z*a.z + a.w*a.w
           + c.x*c.x + c.y*c.y + c.z*c.z + c.w*c.w;
  #pragma unroll
  for (int off = 32; off > 0; off >>= 1) {
    s  += __shfl_xor(s, off);
    ss += __shfl_xor(ss, off);
  }
  float mu  = s * (1.0f/512.0f);
  float var = ss * (1.0f/512.0f) - mu*mu;
  float rstd = rsqrtf(var + 1e-5f);
  const float* gp = g + lane*8;
  const float* bp = bb + lane*8;
  float4 g0 = *(const float4*)gp, g1 = *(const float4*)(gp+4);
  float4 b0 = *(const float4*)bp, b1 = *(const float4*)(bp+4);
  union { ushort u[8]; uint4 v; } pk;
  pk.u[0] = f2bf((a.x-mu)*rstd*g0.x + b0.x);
  pk.u[1] = f2bf((a.y-mu)*rstd*g0.y + b0.y);
  pk.u[2] = f2bf((a.z-mu)*rstd*g0.z + b0.z);
  pk.u[3] = f2bf((a.w-mu)*rstd*g0.w + b0.w);
  pk.u[4] = f2bf((c.x-mu)*rstd*g1.x + b1.x);
  pk.u[5] = f2bf((c.y-mu)*rstd*g1.y + b1.y);
  pk.u[6] = f2bf((c.z-mu)*rstd*g1.z + b1.z);
  pk.u[7] = f2bf((c.w-mu)*rstd*g1.w + b1.w);
  *(uint4*)(out + (size_t)row * Dc + lane * 8) = pk.v;
}

// ---------------- convert / transpose weights to bf16 ---------------------
struct CvtTasks {
  const float* src[16];
  void* dst[16];
  int rows[16], cols[16], mode[16], aux[16], end[16];
  int n;
};

__global__ __launch_bounds__(256) void cvt_kernel(CvtTasks T)
{
  __shared__ ushort tile[64][65];
  int b = blockIdx.x, t = threadIdx.x;
  int ti = 0;
  while (b >= T.end[ti]) ++ti;
  int lb = b - (ti ? T.end[ti-1] : 0);
  const float* src = T.src[ti];
  int mode = T.mode[ti];
  if (mode == 0) {
    int R = T.rows[ti], C = T.cols[ti];
    int tpr = C >> 6;
    int tyy = lb / tpr, txx = lb - tyy * tpr;
    int r0 = tyy << 6, c0 = txx << 6;
    int lr = t >> 4, lc4 = (t & 15) << 2;
    #pragma unroll
    for (int i = 0; i < 4; ++i) {
      int row = i*16 + lr;
      float4 vv = *(const float4*)(src + (size_t)(r0+row)*C + c0 + lc4);
      tile[row][lc4+0] = f2bf(vv.x);
      tile[row][lc4+1] = f2bf(vv.y);
      tile[row][lc4+2] = f2bf(vv.z);
      tile[row][lc4+3] = f2bf(vv.w);
    }
    __syncthreads();
    ushort* dst = (ushort*)T.dst[ti];
    #pragma unroll
    for (int i = 0; i < 4; ++i) {
      int n = i*16 + lr;
      ushort4 o;
      o.x = tile[lc4+0][n];
      o.y = tile[lc4+1][n];
      o.z = tile[lc4+2][n];
      o.w = tile[lc4+3][n];
      *(ushort4*)(dst + (size_t)(c0+n)*R + r0 + lc4) = o;
    }
  } else if (mode == 1) {
    int idx = lb*2048 + t*8;
    float4 v0 = *(const float4*)(src + idx);
    float4 v1 = *(const float4*)(src + idx + 4);
    union { ushort u[8]; uint4 q; } pk;
    pk.u[0]=f2bf(v0.x); pk.u[1]=f2bf(v0.y); pk.u[2]=f2bf(v0.z); pk.u[3]=f2bf(v0.w);
    pk.u[4]=f2bf(v1.x); pk.u[5]=f2bf(v1.y); pk.u[6]=f2bf(v1.z); pk.u[7]=f2bf(v1.w);
    *(uint4*)((ushort*)T.dst[ti] + idx) = pk.q;
  } else {
    if (t < T.cols[ti]) {
      float* d = (float*)T.dst[ti];
      for (int r = 0; r < T.rows[ti]; ++r)
        d[(size_t)(2*r + T.aux[ti]) * T.cols[ti] + t] = src[(size_t)r * T.cols[ti] + t];
    }
  }
}

// ---------------- MFMA bf16 GEMM body: 64x64 tile, BK=64, 4 waves 2x2 ------
template<bool OUT_BF16, bool GELU_>
__device__ __forceinline__ void gemm64_body(
    const ushort* __restrict__ A, int lda,
    const ushort* __restrict__ Bt, int ldb,
    const float* __restrict__ bias,
    void* __restrict__ Cout, int ldc,
    int ksteps, int bm, int bn)
{
  __shared__ __align__(16) char smem[16384];
  char* asB = smem;           // 64 rows x 128B
  char* bsB = smem + 8192;
  int tid = threadIdx.x;
  int lane = tid & 63, wid = tid >> 6;
  int wr = wid >> 1, wc = wid & 1;
  int l15 = lane & 15, kg = lane >> 4;
  f32x4 acc[2][2] = {};
  const ushort* Ab = A + (size_t)bm * lda;
  const ushort* Bb = Bt + (size_t)bn * ldb;
  int r0 = tid >> 3;          // 0..31
  int c16 = tid & 7;
  int wb0 = r0*128 + ((c16*16) ^ ((r0 & 7) << 4));
  int wb1 = (r0+32)*128 + ((c16*16) ^ ((r0 & 7) << 4));
  for (int ks = 0; ks < ksteps; ++ks) {
    int k0 = ks * 64;
    uint4 ra0 = *(const uint4*)(Ab + (size_t)r0*lda + k0 + c16*8);
    uint4 ra1 = *(const uint4*)(Ab + (size_t)(r0+32)*lda + k0 + c16*8);
    uint4 rb0 = *(const uint4*)(Bb + (size_t)r0*ldb + k0 + c16*8);
    uint4 rb1 = *(const uint4*)(Bb + (size_t)(r0+32)*ldb + k0 + c16*8);
    __syncthreads();
    *(uint4*)(asB + wb0) = ra0;  *(uint4*)(asB + wb1) = ra1;
    *(uint4*)(bsB + wb0) = rb0;  *(uint4*)(bsB + wb1) = rb1;
    __syncthreads();
    #pragma unroll
    for (int half = 0; half < 2; ++half) {
      int cb = half*64 + kg*16;
      short8v av[2], bv[2];
      #pragma unroll
      for (int m = 0; m < 2; ++m) {
        int r = wr*32 + m*16 + l15;
        av[m] = *(const short8v*)(asB + r*128 + (cb ^ ((r & 7) << 4)));
      }
      #pragma unroll
      for (int n = 0; n < 2; ++n) {
        int r = wc*32 + n*16 + l15;
        bv[n] = *(const short8v*)(bsB + r*128 + (cb ^ ((r & 7) << 4)));
      }
      #pragma unroll
      for (int m = 0; m < 2; ++m)
        #pragma unroll
        for (int n = 0; n < 2; ++n)
          acc[m][n] = __builtin_amdgcn_mfma_f32_16x16x32_bf16(av[m], bv[n], acc[m][n], 0, 0, 0);
    }
  }
  int orow0 = bm + wr*32 + kg*4;
  int ocol0 = bn + wc*32 + l15;
  #pragma unroll
  for (int m = 0; m < 2; ++m) {
    #pragma unroll
    for (int r = 0; r < 4; ++r) {
      int row = orow0 + m*16 + r;
      #pragma unroll
      for (int n = 0; n < 2; ++n) {
        int col = ocol0 + n*16;
        float val = acc[m][n][r];
        if (bias) val += bias[col];
        if (GELU_) val = gelu_f(val);
        if (OUT_BF16) ((ushort*)Cout)[(size_t)row*ldc + col] = f2bf(val);
        else          ((float*)Cout)[(size_t)row*ldc + col]  = val;
      }
    }
  }
}

// generic z-batched / split-K wrapper
template<bool OUT_BF16, bool GELU_>
__global__ __launch_bounds__(256) void g64(
    const ushort* __restrict__ A, int lda, long Abatch,
    const ushort* __restrict__ Bt, int ldb, long Bbatch,
    const float* __restrict__ bias, int biasStride,
    void* __restrict__ C, int ldc, long Cbatch,
    int ksteps)
{
  int z = blockIdx.z;
  const float* bz = bias ? bias + (size_t)z * biasStride : nullptr;
  void* Cz = OUT_BF16 ? (void*)((ushort*)C + (size_t)z*Cbatch)
                      : (void*)((float*)C + (size_t)z*Cbatch);
  gemm64_body<OUT_BF16, GELU_>(A + (size_t)z*Abatch, lda,
      Bt + (size_t)z*Bbatch, ldb, bz, Cz, ldc, ksteps,
      blockIdx.y*64, blockIdx.x*64);
}

// grouped qkv (z<3, N=512) + Pqk (z in 3..6, N=128)
__global__ __launch_bounds__(256) void qkvp_gemm(
    const ushort* __restrict__ h, const ushort* __restrict__ WcT,
    const float* __restrict__ bc, float* __restrict__ qkv,
    const ushort* __restrict__ absb, const ushort* __restrict__ Wp,
    const float* __restrict__ bqk, float* __restrict__ Pqk)
{
  int z = blockIdx.z;
  const ushort *A, *Bt;
  const float* bias;
  float* C;
  int ldc;
  if (z < 3) {
    A = h; Bt = WcT + (size_t)z*262144; bias = bc + z*512;
    C = qkv + (size_t)z*524288; ldc = 512;
  } else {
    if (blockIdx.x >= 2) return;
    int t = z - 3;
    A = absb + (size_t)(t >> 1)*524288;
    Bt = Wp + (size_t)t*65536;
    bias = bqk + t*128;
    C = Pqk + (size_t)t*131072; ldc = 128;
  }
  gemm64_body<false,false>(A, 512, Bt, 512, bias, C, ldc, 8,
      blockIdx.y*64, blockIdx.x*64);
}

// ---------------- fused: addhead (Pqk += heads) + uin/cvec ----------------
__global__ __launch_bounds__(256) void fused_small(
    const float* __restrict__ q, const float* __restrict__ k,
    float* __restrict__ Pqk, const float* __restrict__ rel_bias,
    const float* __restrict__ brk, ushort* __restrict__ uinb,
    float* __restrict__ cvec)
{
  int tid = threadIdx.x;
  if (blockIdx.x < 1024) {
    int idx = blockIdx.x*256 + tid;
    int dk = idx & 127;
    int rest = idx >> 7;
    int m = rest & 1023;
    int a = rest >> 10;
    Pqk[idx + a*131072]     += q[(size_t)m*512 + a*128 + dk];
    Pqk[idx + (a+1)*131072] += k[(size_t)m*512 + a*128 + dk];
  } else {
    int blkk = blockIdx.x - 1024;           // 0..1023
    int half = tid >> 7, t = tid & 127;
    int row = blkk*2 + half;                // 0..2047 = l*1024+m
    int l = row >> 10, m = row & 1023;
    float val = q[(size_t)m*512 + (2+l)*128 + t] + rel_bias[l*128 + t];
    uinb[(size_t)row*128 + t] = f2bf(val);
    float p = brk[l*128 + t] * val;
    #pragma unroll
    for (int off = 32; off > 0; off >>= 1) p += __shfl_xor(p, off);
    __shared__ float red[4];
    if ((tid & 63) == 0) red[tid >> 6] = p;
    __syncthreads();
    if (tid == 0)   cvec[row] = red[0] + red[1];
    if (tid == 128) cvec[row] = red[2] + red[3];
  }
}

// ---------------- fused rel attention: stream rk + Xq.k + softmax + PV -----
__global__ __launch_bounds__(256) void relattn_kernel(
    const float* __restrict__ rk, const float* __restrict__ u,
    const float* __restrict__ q, const float* __restrict__ k,
    const float* __restrict__ v, const float* __restrict__ cvec,
    const int* __restrict__ mask, ushort* __restrict__ attnob)
{
  int blk = blockIdx.x;               // l*1024 + b*128 + i
  int tid = threadIdx.x;
  int i = blk & 127, b = (blk >> 7) & 7, l = blk >> 10, h = 2 + l;
  int m_i = b*128 + i;
  __shared__ float qs[128], sc[128], ps[128], red[64], pvs[2][128], stat[2];
  int wave = tid >> 6, lane = tid & 63;
  const float* ur = u + ((size_t)l*1024 + m_i)*512 + lane*8;
  float4 uu0 = *(const float4*)ur;
  float4 uu1 = *(const float4*)(ur + 4);
  if (tid < 128) qs[tid] = q[(size_t)m_i*512 + h*128 + tid];
  __syncthreads();
  float xq0 = qs[lane*2], xq1 = qs[lane*2+1];
  const float* base = rk + (size_t)blk*65536 + lane*8;
  const float* kb = k + (size_t)(b*128)*512 + h*128 + lane*2;
  #pragma unroll 2
  for (int jj = 0; jj < 32; ++jj) {
    int j = wave*32 + jj;
    const float* r = base + (size_t)j*512;
    float4 r0 = *(const float4*)r;
    float4 r1 = *(const float4*)(r + 4);
    float2 kk = *(const float2*)(kb + (size_t)j*512);
    float s = r0.x*uu0.x + r0.y*uu0.y + r0.z*uu0.z + r0.w*uu0.w
            + r1.x*uu1.x + r1.y*uu1.y + r1.z*uu1.z + r1.w*uu1.w
            + kk.x*xq0 + kk.y*xq1;
    #pragma unroll
    for (int off = 32; off > 0; off >>= 1) s += __shfl_xor(s, off);
    if (lane == 0) sc[j] = s;
  }
  __syncthreads();
  if (tid < 128) {
    float sv = (sc[tid] + cvec[l*1024 + m_i]) * 0.088388347648318447f;
    if (mask[((size_t)(b*128) + i)*128 + tid] == 0) sv = -1e9f;
    sc[tid] = sv;
  }
  __syncthreads();
  if (tid < 64) red[tid] = fmaxf(sc[tid], sc[tid+64]);
  __syncthreads();
  if (tid < 64) {
    float m = red[tid];
    #pragma unroll
    for (int off = 32; off > 0; off >>= 1) m = fmaxf(m, __shfl_xor(m, off));
    if (tid == 0) stat[0] = m;
  }
  __syncthreads();
  if (tid < 128) ps[tid] = __expf(sc[tid] - stat[0]);
  __syncthreads();
  if (tid < 64) red[tid] = ps[tid] + ps[tid+64];
  __syncthreads();
  if (tid < 64) {
    float s = red[tid];
    #pragma unroll
    for (int off = 32; off > 0; off >>= 1) s += __shfl_xor(s, off);
    if (tid == 0) stat[1] = 1.0f / s;
  }
  __syncthreads();
  int hf = tid >> 7, dk = tid & 127;
  const float* vp = v + (size_t)(b*128 + hf*64)*512 + h*128 + dk;
  float o = 0.0f;
  #pragma unroll 4
  for (int jj = 0; jj < 64; ++jj) o += ps[hf*64 + jj] * vp[(size_t)jj*512];
  pvs[hf][dk] = o;
  __syncthreads();
  if (tid < 128)
    attnob[(size_t)m_i*512 + h*128 + tid] = f2bf((pvs[0][tid] + pvs[1][tid]) * stat[1]);
}

// ---------------- abs-head attention ---------------------------------------
__global__ __launch_bounds__(128) void absattn_kernel(
    const float* __restrict__ Pqk, const float* __restrict__ v,
    const int* __restrict__ mask, ushort* __restrict__ attnob)
{
  int blk = blockIdx.x;            // (b*2 + h)*128 + i
  int tid = threadIdx.x;
  int i = blk & 127;
  int bh = blk >> 7;
  int h = bh & 1;
  int b = bh >> 1;
  __shared__ float qsh[128], psh[128], redh[128];
  int m_i = b*128 + i;
  qsh[tid] = Pqk[(size_t)(2*h)*131072 + (size_t)m_i*128 + tid];
  __syncthreads();
  int j = tid, m_j = b*128 + j;
  const float* krow = Pqk + (size_t)(2*h+1)*131072 + (size_t)m_j*128;
  float dot = 0.0f;
  #pragma unroll
  for (int d = 0; d < 128; d += 4) {
    float4 kv = *(const float4*)(krow + d);
    dot += kv.x*qsh[d] + kv.y*qsh[d+1] + kv.z*qsh[d+2] + kv.w*qsh[d+3];
  }
  float s = dot * 0.088388347648318447f;
  if (mask[((size_t)(b*128) + i)*128 + j] == 0) s = -1e9f;
  redh[tid] = s;
  __syncthreads();
  #pragma unroll
  for (int off = 64; off > 0; off >>= 1) {
    if (tid < off) redh[tid] = fmaxf(redh[tid], redh[tid + off]);
    __syncthreads();
  }
  float mx = redh[0];
  __syncthreads();
  float e = __expf(s - mx);
  psh[tid] = e;
  redh[tid] = e;
  __syncthreads();
  #pragma unroll
  for (int off = 64; off > 0; off >>= 1) {
    if (tid < off) redh[tid] += redh[tid + off];
    __syncthreads();
  }
  float inv = 1.0f / redh[0];
  int dk = tid;
  const float* vp = v + (size_t)b*65536 + h*128 + dk;
  float o = 0.0f;
  for (int jj = 0; jj < 128; ++jj) o += psh[jj] * vp[(size_t)jj*512];
  attnob[(size_t)m_i*512 + h*128 + dk] = f2bf(o * inv);
}

// ---------------- split-K reduce (Wo) + bias + residual + LN2 --------------
__global__ __launch_bounds__(256) void reduce_ln_kernel(
    const float* __restrict__ wpart, const float* __restrict__ bo,
    const float* __restrict__ x, const float* __restrict__ g,
    const float* __restrict__ bb, float* __restrict__ x1,
    ushort* __restrict__ h2)
{
  int gid = blockIdx.x*256 + threadIdx.x;
  int row = gid >> 6, lane = threadIdx.x & 63;
  size_t off = (size_t)row*512 + lane*8;
  float4 a = *(const float4*)(x + off);
  float4 c = *(const float4*)(x + off + 4);
  #pragma unroll
  for (int sk = 0; sk < 4; ++sk) {
    float4 p0 = *(const float4*)(wpart + (size_t)sk*524288 + off);
    float4 p1 = *(const float4*)(wpart + (size_t)sk*524288 + off + 4);
    a.x += p0.x; a.y += p0.y; a.z += p0.z; a.w += p0.w;
    c.x += p1.x; c.y += p1.y; c.z += p1.z; c.w += p1.w;
  }
  float4 bo0 = *(const float4*)(bo + lane*8);
  float4 bo1 = *(const float4*)(bo + lane*8 + 4);
  a.x += bo0.x; a.y += bo0.y; a.z += bo0.z; a.w += bo0.w;
  c.x += bo1.x; c.y += bo1.y; c.z += bo1.z; c.w += bo1.w;
  *(float4*)(x1 + off) = a;
  *(float4*)(x1 + off + 4) = c;
  float s  = a.x + a.y + a.z + a.w + c.x + c.y + c.z + c.w;
  float ss = a.x*a.x + a.y*a.y + a.z*a.z + a.w*a.w
           + c.x*c.x + c.y*c.y + c.z*c.z + c.w*c.w;
  #pragma unroll
  for (int off2 = 32; off2 > 0; off2 >>= 1) {
    s  += __shfl_xor(s, off2);
    ss += __shfl_xor(ss, off2);
  }
  float mu  = s * (1.0f/512.0f);
  float var = ss * (1.0f/512.0f) - mu*mu;
  float rstd = rsqrtf(var + 1e-5f);
  float4 g0 = *(const float4*)(g + lane*8), g1 = *(const float4*)(g + lane*8 + 4);
  float4 b0 = *(const float4*)(bb + lane*8), b1 = *(const float4*)(bb + lane*8 + 4);
  union { ushort u[8]; uint4 v; } pk;
  pk.u[0] = f2bf((a.x-mu)*rstd*g0.x + b0.x);
  pk.u[1] = f2bf((a.y-mu)*rstd*g0.y + b0.y);
  pk.u[2] = f2bf((a.z-mu)*rstd*g0.z + b0.z);
  pk.u[3] = f2bf((a.w-mu)*rstd*g0.w + b0.w);
  pk.u[4] = f2bf((c.x-mu)*rstd*g1.x + b1.x);
  pk.u[5] = f2bf((c.y-mu)*rstd*g1.y + b1.y);
  pk.u[6] = f2bf((c.z-mu)*rstd*g1.z + b1.z);
  pk.u[7] = f2bf((c.w-mu)*rstd*g1.w + b1.w);
  *(uint4*)(h2 + off) = pk.v;
}

// ---------------- split-K reduce (FFN2) + bias + residual -> out -----------
__global__ __launch_bounds__(256) void reduce_out_kernel(
    const float* __restrict__ fpart, const float* __restrict__ b2,
    const float* __restrict__ x1, float* __restrict__ out)
{
  int idx = blockIdx.x*256 + threadIdx.x;     // x4 floats
  size_t o4 = (size_t)idx*4;
  float4 s = *(const float4*)(x1 + o4);
  #pragma unroll
  for (int sk = 0; sk < 4; ++sk) {
    float4 p = *(const float4*)(fpart + (size_t)sk*524288 + o4);
    s.x += p.x; s.y += p.y; s.z += p.z; s.w += p.w;
  }
  float4 bv = *(const float4*)(b2 + ((idx & 127)*4));
  s.x += bv.x; s.y += bv.y; s.z += bv.z; s.w += bv.w;
  *(float4*)(out + o4) = s;
}

// ---------------------------------------------------------------------------
extern "C" void kernel_launch(void* const* d_in, const int* in_sizes, int n_in,
                              void* d_out, int out_size, void* d_ws, size_t ws_size,
                              hipStream_t stream)
{
  const float* x         = (const float*)d_in[0];
  const int*   mask      = (const int*)  d_in[1];
  const float* abs_kernel= (const float*)d_in[2];
  const float* rel_kernel= (const float*)d_in[3];
  const float* Wc        = (const float*)d_in[4];
  const float* bc        = (const float*)d_in[5];
  const float* Wpq       = (const float*)d_in[6];
  const float* bpq       = (const float*)d_in[7];
  const float* Wpk       = (const float*)d_in[8];
  const float* bpk       = (const float*)d_in[9];
  const float* Wrk       = (const float*)d_in[10];
  const float* brk       = (const float*)d_in[11];
  const float* rel_bias  = (const float*)d_in[12];
  const float* Wo        = (const float*)d_in[13];
  const float* bo        = (const float*)d_in[14];
  const float* W1        = (const float*)d_in[15];
  const float* b1        = (const float*)d_in[16];
  const float* W2        = (const float*)d_in[17];
  const float* b2        = (const float*)d_in[18];
  const float* ln1g      = (const float*)d_in[19];
  const float* ln1b      = (const float*)d_in[20];
  const float* ln2g      = (const float*)d_in[21];
  const float* ln2b      = (const float*)d_in[22];

  float* ws = (float*)d_ws;
  float* q      = ws;               // 524288  (q|k|v contiguous)
  float* kbuf   = ws + 524288;
  float* v      = ws + 1048576;
  float* Pqk    = ws + 1572864;     // 524288
  float* u      = ws + 2097152;     // 1048576
  float* x1     = ws + 3145728;     // 524288
  float* cvec   = ws + 3670016;     // 2048
  float* bqk    = ws + 3672064;     // 512
  float* wpart  = ws + 3672576;     // 2097152 (reused as fpart)
  float* fpart  = wpart;
  ushort* bf    = (ushort*)(ws + 5769728);
  ushort* h     = bf;               // 524288
  ushort* h2    = bf + 524288;
  ushort* uinb  = bf + 1048576;     // 262144
  ushort* attnob= bf + 1310720;     // 524288
  ushort* f1    = bf + 1835008;     // 2097152
  ushort* absb  = bf + 3932160;     // 1048576
  ushort* WcT   = bf + 4980736;     // 786432
  ushort* Wp    = bf + 5767168;     // 262144
  ushort* Wrkb  = bf + 6029312;     // 131072
  ushort* WoT   = bf + 6160384;     // 262144
  ushort* W1T   = bf + 6422528;     // 1048576
  ushort* W2T   = bf + 7471104;     // 1048576
  float* out    = (float*)d_out;

  // ---- convert/transpose task table ----
  CvtTasks T{};
  int nb = 0, ti = 0;
  auto addTr = [&](const float* s, ushort* d, int R, int C) {
    T.src[ti]=s; T.dst[ti]=d; T.rows[ti]=R; T.cols[ti]=C; T.mode[ti]=0; T.aux[ti]=0;
    nb += (R/64)*(C/64); T.end[ti]=nb; ++ti;
  };
  auto addCv = [&](const float* s, ushort* d, int n) {
    T.src[ti]=s; T.dst[ti]=d; T.rows[ti]=n; T.cols[ti]=0; T.mode[ti]=1; T.aux[ti]=0;
    nb += n/2048; T.end[ti]=nb; ++ti;
  };
  auto addBi = [&](const float* s, float* d, int aux) {
    T.src[ti]=s; T.dst[ti]=d; T.rows[ti]=2; T.cols[ti]=128; T.mode[ti]=2; T.aux[ti]=aux;
    nb += 1; T.end[ti]=nb; ++ti;
  };
  for (int c = 0; c < 3; ++c) addTr(Wc + (size_t)c*262144, WcT + (size_t)c*262144, 512, 512);
  addTr(Wo, WoT, 512, 512);
  addTr(W1, W1T, 512, 2048);
  addTr(W2, W2T, 2048, 512);
  for (int a = 0; a < 2; ++a) addTr(Wpq + (size_t)a*65536, Wp + (size_t)(2*a)*65536, 512, 128);
  for (int a = 0; a < 2; ++a) addTr(Wpk + (size_t)a*65536, Wp + (size_t)(2*a+1)*65536, 512, 128);
  addCv(abs_kernel, absb, 1048576);
  addCv(Wrk, Wrkb, 131072);
  addBi(bpq, bqk, 0);
  addBi(bpk, bqk, 1);
  T.n = ti;

  cvt_kernel<<<nb, 256, 0, stream>>>(T);

  // LN1 -> h (bf16)
  ln_kernel<<<256, 256, 0, stream>>>(x, ln1g, ln1b, h);

  // grouped qkv + Pqk (512 useful blocks)
  qkvp_gemm<<<dim3(8,16,7), 256, 0, stream>>>(h, WcT, bc, q, absb, Wp, bqk, Pqk);

  // addhead + uin/cvec
  fused_small<<<2048, 256, 0, stream>>>(q, kbuf, Pqk, rel_bias, brk, uinb, cvec);

  // u = uin @ Wrk^T  (z = l, K=128)
  g64<false,false><<<dim3(8,16,2), 256, 0, stream>>>(
      uinb, 128, 131072, Wrkb, 128, 65536, nullptr, 0, u, 512, 524288, 2);

  // fused rel attention (streams 537MB rel_kernel)
  relattn_kernel<<<2048, 256, 0, stream>>>(rel_kernel, u, q, kbuf, v, cvec, mask, attnob);

  // abs-head attention
  absattn_kernel<<<2048, 128, 0, stream>>>(Pqk, v, mask, attnob);

  // Wo projection, split-K 4 (z = k-chunk), partials fp32
  g64<false,false><<<dim3(8,16,4), 256, 0, stream>>>(
      attnob, 512, 128, WoT, 512, 128, nullptr, 0, wpart, 512, 524288, 2);

  // reduce + bo + residual(x) + LN2 -> x1, h2
  reduce_ln_kernel<<<256, 256, 0, stream>>>(wpart, bo, x, ln2g, ln2b, x1, h2);

  // FFN1 + GELU -> f1 (bf16), 512 blocks
  g64<true,true><<<dim3(32,16,1), 256, 0, stream>>>(
      h2, 512, 0, W1T, 512, 0, b1, 0, f1, 2048, 0, 8);

  // FFN2 split-K 4 -> fpart
  g64<false,false><<<dim3(8,16,4), 256, 0, stream>>>(
      f1, 2048, 512, W2T, 2048, 512, nullptr, 0, fpart, 512, 524288, 8);

  // reduce + b2 + residual(x1) -> out
  reduce_out_kernel<<<512, 256, 0, stream>>>(fpart, b2, x1, out);
}